// Round 10
// baseline (165.192 us; speedup 1.0000x reference)
//
#include <hip/hip_runtime.h>
#include <float.h>
#include <stdint.h>

#define EMB_DIM  300
#define MAX_LEN  128
#define HIDDEN   1000
#define NCLS     5
#define VOCAB_SZ 50000
#define KPAD     640     // 600 padded to 10*64
#define NPAD     1024    // 1000 padded to 8*128
#define EMBPAD   320     // 300 dims padded to 320 shorts = 640 B = 5 x 128 B lines

typedef float    f32x4  __attribute__((ext_vector_type(4)));
typedef __bf16   bf16x8 __attribute__((ext_vector_type(8)));
typedef unsigned short ushort8v __attribute__((ext_vector_type(8)));

#define CONV_BLOCKS ((VOCAB_SZ * (EMBPAD / 4) + 255) / 256)   // 15625

__device__ __forceinline__ unsigned short f2bf(float f) {
    union { float f; uint32_t u; } v; v.f = f;
    uint32_t u = v.u;
    return (unsigned short)((u + 0x7FFFu + ((u >> 16) & 1u)) >> 16);   // RNE
}
__device__ __forceinline__ float bf2f(unsigned short h) {
    union { uint32_t u; float f; } v; v.u = ((uint32_t)h) << 16;
    return v.f;
}

// ---------------------------------------------------------------------------
// prep_all: one dispatch for emb conversion + both weight preps.
// ---------------------------------------------------------------------------
__global__ __launch_bounds__(256) void prep_all(
    const float* __restrict__ emb, unsigned short* __restrict__ embb,
    const float* __restrict__ W1, unsigned short* __restrict__ Bt,
    const float* __restrict__ W2, unsigned short* __restrict__ W2t)
{
    __shared__ float t[32][33];
    const int blk = blockIdx.x;

    if (blk < CONV_BLOCKS) {
        const int i = blk * 256 + threadIdx.x;     // chunk of 4 shorts
        if (i >= VOCAB_SZ * (EMBPAD / 4)) return;
        const int v  = i / (EMBPAD / 4);
        const int ch = i - v * (EMBPAD / 4);
        ushort4 o = {0, 0, 0, 0};
        if (ch < 75) {
            const float4 f = *(const float4*)(emb + (size_t)v * EMB_DIM + ch * 4);
            o.x = f2bf(f.x); o.y = f2bf(f.y); o.z = f2bf(f.z); o.w = f2bf(f.w);
        }
        *(ushort4*)(embb + (size_t)v * EMBPAD + ch * 4) = o;
        return;
    }
    const int pb = blk - CONV_BLOCKS;
    if (pb >= 640) {                               // W2T: 20 blocks
        const int i = (pb - 640) * 256 + threadIdx.x;    // [0, 5120)
        const int c = i >> 10, k = i & 1023;
        const float v = (k < HIDDEN) ? W2[(size_t)k * NCLS + c] : 0.f;
        W2t[(size_t)c * 1024 + k] = f2bf(v);
        return;
    }
    // W1 transpose: pb -> (px, py) in (32, 20)
    const int px = pb & 31, py = pb >> 5;
    const int tx = threadIdx.x & 31, ty = threadIdx.x >> 5;   // 32 x 8
    const int n0 = px * 32, k0 = py * 32;
    #pragma unroll
    for (int i = 0; i < 4; ++i) {
        int k = k0 + ty + i * 8, n = n0 + tx;
        t[ty + i * 8][tx] = (k < 600 && n < HIDDEN) ? W1[(size_t)k * HIDDEN + n] : 0.f;
    }
    __syncthreads();
    #pragma unroll
    for (int i = 0; i < 4; ++i) {
        int n = n0 + ty + i * 8, k = k0 + tx;
        Bt[(size_t)n * KPAD + k] = f2bf(t[tx][ty + i * 8]);
    }
}

// ---------------------------------------------------------------------------
// pool_bf16: gather + masked avg/max over bf16 table -> rep bf16 [B][640].
// ---------------------------------------------------------------------------
__global__ __launch_bounds__(128) void pool_bf16(
    const int* __restrict__ x, const int* __restrict__ lengths,
    const unsigned short* __restrict__ embb, unsigned short* __restrict__ rep)
{
    const int b = blockIdx.x;
    const int t = threadIdx.x;

    __shared__ int sidx[MAX_LEN];
    sidx[t] = x[b * MAX_LEN + t];
    __syncthreads();

    unsigned short* rb = rep + (size_t)b * KPAD;

    if (t >= 75) {
        if (t < 85) {                      // zero pad cols 600..639
            ushort4 z = {0, 0, 0, 0};
            *(ushort4*)(rb + 600 + (t - 75) * 4) = z;
        }
        return;
    }

    int L = lengths[b];
    L = max(1, min(L, MAX_LEN));

    const int d = t * 4;
    float4 s  = {0.f, 0.f, 0.f, 0.f};
    float4 mx = {-FLT_MAX, -FLT_MAX, -FLT_MAX, -FLT_MAX};

    int i = 0;
    for (; i + 2 <= L; i += 2) {
        int i0 = max(0, min(sidx[i],     VOCAB_SZ - 1));
        int i1 = max(0, min(sidx[i + 1], VOCAB_SZ - 1));
        const ushort4 a = *(const ushort4*)(embb + (size_t)i0 * EMBPAD + d);
        const ushort4 c = *(const ushort4*)(embb + (size_t)i1 * EMBPAD + d);
        float a0 = bf2f(a.x), a1 = bf2f(a.y), a2 = bf2f(a.z), a3 = bf2f(a.w);
        float c0 = bf2f(c.x), c1 = bf2f(c.y), c2 = bf2f(c.z), c3 = bf2f(c.w);
        s.x += a0 + c0; s.y += a1 + c1; s.z += a2 + c2; s.w += a3 + c3;
        mx.x = fmaxf(mx.x, fmaxf(a0, c0)); mx.y = fmaxf(mx.y, fmaxf(a1, c1));
        mx.z = fmaxf(mx.z, fmaxf(a2, c2)); mx.w = fmaxf(mx.w, fmaxf(a3, c3));
    }
    if (i < L) {
        int i0 = max(0, min(sidx[i], VOCAB_SZ - 1));
        const ushort4 a = *(const ushort4*)(embb + (size_t)i0 * EMBPAD + d);
        float a0 = bf2f(a.x), a1 = bf2f(a.y), a2 = bf2f(a.z), a3 = bf2f(a.w);
        s.x += a0; s.y += a1; s.z += a2; s.w += a3;
        mx.x = fmaxf(mx.x, a0); mx.y = fmaxf(mx.y, a1);
        mx.z = fmaxf(mx.z, a2); mx.w = fmaxf(mx.w, a3);
    }

    const float inv = 1.0f / (float)L;
    ushort4 av, mv;
    av.x = f2bf(s.x * inv); av.y = f2bf(s.y * inv);
    av.z = f2bf(s.z * inv); av.w = f2bf(s.w * inv);
    mv.x = f2bf(mx.x); mv.y = f2bf(mx.y); mv.z = f2bf(mx.z); mv.w = f2bf(mx.w);
    *(ushort4*)(rb + d)       = av;     // avg -> [0,300)
    *(ushort4*)(rb + 300 + d) = mv;     // max -> [300,600)
}

// ---------------------------------------------------------------------------
// pool_f32 (fallback if ws too small for the bf16 table).
// ---------------------------------------------------------------------------
__global__ __launch_bounds__(128) void pool_f32(
    const int* __restrict__ x, const int* __restrict__ lengths,
    const float* __restrict__ emb, unsigned short* __restrict__ rep)
{
    const int b = blockIdx.x;
    const int t = threadIdx.x;

    __shared__ int sidx[MAX_LEN];
    sidx[t] = x[b * MAX_LEN + t];
    __syncthreads();

    unsigned short* rb = rep + (size_t)b * KPAD;

    if (t >= 75) {
        if (t < 85) {
            ushort4 z = {0, 0, 0, 0};
            *(ushort4*)(rb + 600 + (t - 75) * 4) = z;
        }
        return;
    }

    int L = lengths[b];
    L = max(1, min(L, MAX_LEN));

    const int d = t * 4;
    float4 s  = {0.f, 0.f, 0.f, 0.f};
    float4 mx = {-FLT_MAX, -FLT_MAX, -FLT_MAX, -FLT_MAX};

    for (int i = 0; i < L; ++i) {
        int idx = max(0, min(sidx[i], VOCAB_SZ - 1));
        const float4 v = *(const float4*)(emb + (size_t)idx * EMB_DIM + d);
        s.x += v.x; s.y += v.y; s.z += v.z; s.w += v.w;
        mx.x = fmaxf(mx.x, v.x); mx.y = fmaxf(mx.y, v.y);
        mx.z = fmaxf(mx.z, v.z); mx.w = fmaxf(mx.w, v.w);
    }

    const float inv = 1.0f / (float)L;
    ushort4 av, mv;
    av.x = f2bf(s.x * inv); av.y = f2bf(s.y * inv);
    av.z = f2bf(s.z * inv); av.w = f2bf(s.w * inv);
    mv.x = f2bf(mx.x); mv.y = f2bf(mx.y); mv.z = f2bf(mx.z); mv.w = f2bf(mx.w);
    *(ushort4*)(rb + d)       = av;
    *(ushort4*)(rb + 300 + d) = mv;
}

// ---------------------------------------------------------------------------
// gemm1p v2: partials[nb] = relu(rep @ W1 + b1)[:, nb] @ W2  (fused GEMM2)
// 128x128 tile (traffic 84 MB vs 160 MB at 64x64 -- fabric-BW bound),
// BK=64, 512 thr = 8 waves (2m x 4n), wave tile 64x32, LDS 64 KB dbuf,
// global_load_lds(16B) staging, 1 chunk slot per thread per tile.
// grid (8, 32) = 256 blocks = 1/CU (balanced 32/XCD).
// ---------------------------------------------------------------------------
#define BM 128
#define BN 128
#define BK 64
#define GNB (NPAD / BN)   // 8

__global__ __launch_bounds__(512, 2) void gemm1p(
    const unsigned short* __restrict__ A,    // rep  [M][640] bf16
    const unsigned short* __restrict__ Bt,   // W1T  [1024][640] bf16
    const float* __restrict__ bias,          // b1 [1000]
    const unsigned short* __restrict__ W2t,  // [5][1024] bf16
    float* __restrict__ partials,            // [8][M][5]
    int M)
{
    __shared__ unsigned short As[2][BM * BK];   // 16 KB each buffer
    __shared__ unsigned short Bs[2][BN * BK];   // 16 KB each buffer

    const int tid  = threadIdx.x;
    const int wv   = tid >> 6;          // 0..7
    const int lane = tid & 63;
    const int bm   = blockIdx.y * BM;
    const int bn   = blockIdx.x * BN;
    const int wm   = (wv & 1) * 64;     // wave m-origin in tile
    const int wn   = (wv >> 1) * 32;    // wave n-origin in tile

    f32x4 acc[4][2] = {};

    // Tile = 128 rows x 128 B = 1024 chunks of 16 B; 16 instr-slots of 64.
    auto stage = [&](int buf, int k0) {
        #pragma unroll
        for (int j = 0; j < 2; ++j) {
            int s   = wv * 2 + j;                 // slot 0..15
            int ci  = s * 64 + lane;              // chunk 0..1023
            int row = ci >> 3, c = ci & 7;
            const unsigned short* g = A + (size_t)(bm + row) * KPAD + k0 + c * 8;
            unsigned short* l = &As[buf][s * 512];   // 1024 B per slot
            __builtin_amdgcn_global_load_lds(g, l, 16, 0, 0);
        }
        #pragma unroll
        for (int j = 0; j < 2; ++j) {
            int s   = wv * 2 + j;
            int ci  = s * 64 + lane;
            int row = ci >> 3, c = ci & 7;
            const unsigned short* g = Bt + (size_t)(bn + row) * KPAD + k0 + c * 8;
            unsigned short* l = &Bs[buf][s * 512];
            __builtin_amdgcn_global_load_lds(g, l, 16, 0, 0);
        }
    };

    stage(0, 0);
    int cur = 0;
    const int q = lane >> 4, r16 = lane & 15;

    #pragma unroll 1
    for (int it = 0; it < KPAD / BK; ++it) {
        __syncthreads();
        if (it + 1 < KPAD / BK) stage(cur ^ 1, (it + 1) * BK);

        #pragma unroll
        for (int ks = 0; ks < BK; ks += 32) {
            bf16x8 af[4], bfr[2];
            #pragma unroll
            for (int mi = 0; mi < 4; ++mi)
                af[mi] = *(const bf16x8*)&As[cur][(wm + mi * 16 + r16) * BK + ks + q * 8];
            #pragma unroll
            for (int nj = 0; nj < 2; ++nj)
                bfr[nj] = *(const bf16x8*)&Bs[cur][(wn + nj * 16 + r16) * BK + ks + q * 8];
            #pragma unroll
            for (int mi = 0; mi < 4; ++mi)
                #pragma unroll
                for (int nj = 0; nj < 2; ++nj)
                    acc[mi][nj] = __builtin_amdgcn_mfma_f32_16x16x32_bf16(
                        af[mi], bfr[nj], acc[mi][nj], 0, 0, 0);
        }
        cur ^= 1;
    }

    // ---- fused epilogue: h = relu(acc + b1); p = h @ W2T ----
    // C/D layout: col(n) = r16, row(m) = q*4 + reg (+ mi*16).
    float bv[2], w2v[2][NCLS];
    #pragma unroll
    for (int nj = 0; nj < 2; ++nj) {
        int n = bn + wn + nj * 16 + r16;
        if (n < HIDDEN) {
            bv[nj] = bias[n];
            #pragma unroll
            for (int c = 0; c < NCLS; ++c) w2v[nj][c] = bf2f(W2t[c * 1024 + n]);
        } else {
            bv[nj] = 0.f;
            #pragma unroll
            for (int c = 0; c < NCLS; ++c) w2v[nj][c] = 0.f;
        }
    }

    __syncthreads();                     // LDS reuse: As becomes float scratch
    float* pl = (float*)As;              // [4 wn-groups][128 rows][5] = 10240 B

    #pragma unroll
    for (int mi = 0; mi < 4; ++mi) {
        #pragma unroll
        for (int r = 0; r < 4; ++r) {
            float p[NCLS] = {0.f, 0.f, 0.f, 0.f, 0.f};
            #pragma unroll
            for (int nj = 0; nj < 2; ++nj) {
                float h = fmaxf(acc[mi][nj][r] + bv[nj], 0.f);
                #pragma unroll
                for (int c = 0; c < NCLS; ++c) p[c] += h * w2v[nj][c];
            }
            #pragma unroll
            for (int off = 1; off < 16; off <<= 1)
                #pragma unroll
                for (int c = 0; c < NCLS; ++c)
                    p[c] += __shfl_xor(p[c], off, 64);
            if (r16 == 0) {
                int row = wm + mi * 16 + q * 4 + r;        // 0..127 in tile
                int g   = wv >> 1;                          // wn-group 0..3
                #pragma unroll
                for (int c = 0; c < NCLS; ++c)
                    pl[((size_t)g * BM + row) * NCLS + c] = p[c];
            }
        }
    }
    __syncthreads();

    // combine the 4 wn-groups; 128*5 = 640 entries over 512 threads (strided).
    for (int e = tid; e < BM * NCLS; e += 512) {
        int row = e / NCLS, c = e - row * NCLS;
        float v = pl[((size_t)0 * BM + row) * NCLS + c]
                + pl[((size_t)1 * BM + row) * NCLS + c]
                + pl[((size_t)2 * BM + row) * NCLS + c]
                + pl[((size_t)3 * BM + row) * NCLS + c];
        partials[(size_t)blockIdx.x * M * NCLS + (size_t)(bm + row) * NCLS + c] = v;
    }
}

// ---------------------------------------------------------------------------
// reduce_out: out[m][c] = b2[c] + sum_nb partials[nb][m][c]
// ---------------------------------------------------------------------------
__global__ __launch_bounds__(256) void reduce_out(
    const float* __restrict__ partials, const float* __restrict__ b2,
    float* __restrict__ out, int M)
{
    const int i = blockIdx.x * 256 + threadIdx.x;
    if (i >= M * NCLS) return;
    const int c = i % NCLS;
    float s = b2[c];
    #pragma unroll
    for (int nb = 0; nb < GNB; ++nb)
        s += partials[(size_t)nb * M * NCLS + i];
    out[i] = s;
}

// ---------------------------------------------------------------------------
extern "C" void kernel_launch(void* const* d_in, const int* in_sizes, int n_in,
                              void* d_out, int out_size, void* d_ws, size_t ws_size,
                              hipStream_t stream)
{
    const int*   x       = (const int*)d_in[0];
    const int*   lengths = (const int*)d_in[1];
    const float* emb     = (const float*)d_in[2];
    const float* W1      = (const float*)d_in[3];
    const float* b1      = (const float*)d_in[4];
    const float* W2      = (const float*)d_in[5];
    const float* b2      = (const float*)d_in[6];
    float*       out     = (float*)d_out;

    const int B = in_sizes[1];               // 4096

    unsigned short* rep      = (unsigned short*)d_ws;         // [B][640]
    unsigned short* w1t      = rep + (size_t)B * KPAD;        // [1024][640]
    unsigned short* w2t      = w1t + (size_t)NPAD * KPAD;     // [5][1024]
    unsigned short* embb     = w2t + (size_t)NCLS * 1024;     // [50000][320]
    float*          partials = (float*)(embb + (size_t)VOCAB_SZ * EMBPAD); // [8][B][5]

    const size_t need = ((size_t)B * KPAD + (size_t)NPAD * KPAD + NCLS * 1024
                         + (size_t)VOCAB_SZ * EMBPAD) * 2
                        + (size_t)GNB * B * NCLS * 4;

    prep_all<<<CONV_BLOCKS + 660, 256, 0, stream>>>(emb, embb, W1, w1t, W2, w2t);

    if (ws_size >= need) {
        pool_bf16<<<B, 128, 0, stream>>>(x, lengths, embb, rep);
    } else {
        pool_f32<<<B, 128, 0, stream>>>(x, lengths, emb, rep);
    }

    dim3 g1(GNB, B / BM);                    // (8, 32) = 256 blocks
    gemm1p<<<g1, 512, 0, stream>>>(rep, w1t, b1, w2t, partials, B);

    reduce_out<<<(B * NCLS + 255) / 256, 256, 0, stream>>>(partials, b2, out, B);
}

// Round 11
// 161.340 us; speedup vs baseline: 1.0239x; 1.0239x over previous
//
#include <hip/hip_runtime.h>
#include <float.h>
#include <stdint.h>

#define EMB_DIM  300
#define MAX_LEN  128
#define HIDDEN   1000
#define NCLS     5
#define VOCAB_SZ 50000
#define KPAD     640     // 600 padded to 10*64
#define NPAD     1024    // 1000 padded to 16*64
#define EMBPAD   320     // 300 dims padded to 320 shorts = 640 B = 5 x 128 B lines

typedef float    f32x4  __attribute__((ext_vector_type(4)));
typedef __bf16   bf16x8 __attribute__((ext_vector_type(8)));
typedef unsigned short ushort8v __attribute__((ext_vector_type(8)));

#define CONV_BLOCKS ((VOCAB_SZ * (EMBPAD / 4) + 255) / 256)   // 15625

__device__ __forceinline__ unsigned short f2bf(float f) {
    union { float f; uint32_t u; } v; v.f = f;
    uint32_t u = v.u;
    return (unsigned short)((u + 0x7FFFu + ((u >> 16) & 1u)) >> 16);   // RNE
}
__device__ __forceinline__ float bf2f(unsigned short h) {
    union { uint32_t u; float f; } v; v.u = ((uint32_t)h) << 16;
    return v.f;
}

// ---------------------------------------------------------------------------
// prep_all: one dispatch for emb conversion + both weight preps.
// ---------------------------------------------------------------------------
__global__ __launch_bounds__(256) void prep_all(
    const float* __restrict__ emb, unsigned short* __restrict__ embb,
    const float* __restrict__ W1, unsigned short* __restrict__ Bt,
    const float* __restrict__ W2, unsigned short* __restrict__ W2t)
{
    __shared__ float t[32][33];
    const int blk = blockIdx.x;

    if (blk < CONV_BLOCKS) {
        const int i = blk * 256 + threadIdx.x;     // chunk of 4 shorts
        if (i >= VOCAB_SZ * (EMBPAD / 4)) return;
        const int v  = i / (EMBPAD / 4);
        const int ch = i - v * (EMBPAD / 4);
        ushort4 o = {0, 0, 0, 0};
        if (ch < 75) {
            const float4 f = *(const float4*)(emb + (size_t)v * EMB_DIM + ch * 4);
            o.x = f2bf(f.x); o.y = f2bf(f.y); o.z = f2bf(f.z); o.w = f2bf(f.w);
        }
        *(ushort4*)(embb + (size_t)v * EMBPAD + ch * 4) = o;
        return;
    }
    const int pb = blk - CONV_BLOCKS;
    if (pb >= 640) {                               // W2T: 20 blocks
        const int i = (pb - 640) * 256 + threadIdx.x;    // [0, 5120)
        const int c = i >> 10, k = i & 1023;
        const float v = (k < HIDDEN) ? W2[(size_t)k * NCLS + c] : 0.f;
        W2t[(size_t)c * 1024 + k] = f2bf(v);
        return;
    }
    // W1 transpose: pb -> (px, py) in (32, 20)
    const int px = pb & 31, py = pb >> 5;
    const int tx = threadIdx.x & 31, ty = threadIdx.x >> 5;   // 32 x 8
    const int n0 = px * 32, k0 = py * 32;
    #pragma unroll
    for (int i = 0; i < 4; ++i) {
        int k = k0 + ty + i * 8, n = n0 + tx;
        t[ty + i * 8][tx] = (k < 600 && n < HIDDEN) ? W1[(size_t)k * HIDDEN + n] : 0.f;
    }
    __syncthreads();
    #pragma unroll
    for (int i = 0; i < 4; ++i) {
        int n = n0 + ty + i * 8, k = k0 + tx;
        Bt[(size_t)n * KPAD + k] = f2bf(t[tx][ty + i * 8]);
    }
}

// ---------------------------------------------------------------------------
// pool_bf16 v2: gather + masked avg/max -> rep bf16 [B][640].
// Token loop unrolled x4 (4 independent gathers in flight). Evidence:
// 1-deep = 54 us, 2-deep = 26 us (latency-bound, linear in unroll depth).
// ---------------------------------------------------------------------------
__global__ __launch_bounds__(128) void pool_bf16(
    const int* __restrict__ x, const int* __restrict__ lengths,
    const unsigned short* __restrict__ embb, unsigned short* __restrict__ rep)
{
    const int b = blockIdx.x;
    const int t = threadIdx.x;

    __shared__ int sidx[MAX_LEN];
    sidx[t] = x[b * MAX_LEN + t];
    __syncthreads();

    unsigned short* rb = rep + (size_t)b * KPAD;

    if (t >= 75) {
        if (t < 85) {                      // zero pad cols 600..639
            ushort4 z = {0, 0, 0, 0};
            *(ushort4*)(rb + 600 + (t - 75) * 4) = z;
        }
        return;
    }

    int L = lengths[b];
    L = max(1, min(L, MAX_LEN));

    const int d = t * 4;
    float4 s  = {0.f, 0.f, 0.f, 0.f};
    float4 mx = {-FLT_MAX, -FLT_MAX, -FLT_MAX, -FLT_MAX};

    int i = 0;
    for (; i + 4 <= L; i += 4) {
        int i0 = max(0, min(sidx[i],     VOCAB_SZ - 1));
        int i1 = max(0, min(sidx[i + 1], VOCAB_SZ - 1));
        int i2 = max(0, min(sidx[i + 2], VOCAB_SZ - 1));
        int i3 = max(0, min(sidx[i + 3], VOCAB_SZ - 1));
        const ushort4 v0 = *(const ushort4*)(embb + (size_t)i0 * EMBPAD + d);
        const ushort4 v1 = *(const ushort4*)(embb + (size_t)i1 * EMBPAD + d);
        const ushort4 v2 = *(const ushort4*)(embb + (size_t)i2 * EMBPAD + d);
        const ushort4 v3 = *(const ushort4*)(embb + (size_t)i3 * EMBPAD + d);
        float a0 = bf2f(v0.x), a1 = bf2f(v0.y), a2 = bf2f(v0.z), a3 = bf2f(v0.w);
        float b0 = bf2f(v1.x), b1 = bf2f(v1.y), b2 = bf2f(v1.z), b3 = bf2f(v1.w);
        float c0 = bf2f(v2.x), c1 = bf2f(v2.y), c2 = bf2f(v2.z), c3 = bf2f(v2.w);
        float e0 = bf2f(v3.x), e1 = bf2f(v3.y), e2 = bf2f(v3.z), e3 = bf2f(v3.w);
        s.x += (a0 + b0) + (c0 + e0); s.y += (a1 + b1) + (c1 + e1);
        s.z += (a2 + b2) + (c2 + e2); s.w += (a3 + b3) + (c3 + e3);
        mx.x = fmaxf(mx.x, fmaxf(fmaxf(a0, b0), fmaxf(c0, e0)));
        mx.y = fmaxf(mx.y, fmaxf(fmaxf(a1, b1), fmaxf(c1, e1)));
        mx.z = fmaxf(mx.z, fmaxf(fmaxf(a2, b2), fmaxf(c2, e2)));
        mx.w = fmaxf(mx.w, fmaxf(fmaxf(a3, b3), fmaxf(c3, e3)));
    }
    for (; i < L; ++i) {
        int i0 = max(0, min(sidx[i], VOCAB_SZ - 1));
        const ushort4 a = *(const ushort4*)(embb + (size_t)i0 * EMBPAD + d);
        float a0 = bf2f(a.x), a1 = bf2f(a.y), a2 = bf2f(a.z), a3 = bf2f(a.w);
        s.x += a0; s.y += a1; s.z += a2; s.w += a3;
        mx.x = fmaxf(mx.x, a0); mx.y = fmaxf(mx.y, a1);
        mx.z = fmaxf(mx.z, a2); mx.w = fmaxf(mx.w, a3);
    }

    const float inv = 1.0f / (float)L;
    ushort4 av, mv;
    av.x = f2bf(s.x * inv); av.y = f2bf(s.y * inv);
    av.z = f2bf(s.z * inv); av.w = f2bf(s.w * inv);
    mv.x = f2bf(mx.x); mv.y = f2bf(mx.y); mv.z = f2bf(mx.z); mv.w = f2bf(mx.w);
    *(ushort4*)(rb + d)       = av;     // avg -> [0,300)
    *(ushort4*)(rb + 300 + d) = mv;     // max -> [300,600)
}

// ---------------------------------------------------------------------------
// pool_f32 (fallback if ws too small for the bf16 table).
// ---------------------------------------------------------------------------
__global__ __launch_bounds__(128) void pool_f32(
    const int* __restrict__ x, const int* __restrict__ lengths,
    const float* __restrict__ emb, unsigned short* __restrict__ rep)
{
    const int b = blockIdx.x;
    const int t = threadIdx.x;

    __shared__ int sidx[MAX_LEN];
    sidx[t] = x[b * MAX_LEN + t];
    __syncthreads();

    unsigned short* rb = rep + (size_t)b * KPAD;

    if (t >= 75) {
        if (t < 85) {
            ushort4 z = {0, 0, 0, 0};
            *(ushort4*)(rb + 600 + (t - 75) * 4) = z;
        }
        return;
    }

    int L = lengths[b];
    L = max(1, min(L, MAX_LEN));

    const int d = t * 4;
    float4 s  = {0.f, 0.f, 0.f, 0.f};
    float4 mx = {-FLT_MAX, -FLT_MAX, -FLT_MAX, -FLT_MAX};

    for (int i = 0; i < L; ++i) {
        int idx = max(0, min(sidx[i], VOCAB_SZ - 1));
        const float4 v = *(const float4*)(emb + (size_t)idx * EMB_DIM + d);
        s.x += v.x; s.y += v.y; s.z += v.z; s.w += v.w;
        mx.x = fmaxf(mx.x, v.x); mx.y = fmaxf(mx.y, v.y);
        mx.z = fmaxf(mx.z, v.z); mx.w = fmaxf(mx.w, v.w);
    }

    const float inv = 1.0f / (float)L;
    ushort4 av, mv;
    av.x = f2bf(s.x * inv); av.y = f2bf(s.y * inv);
    av.z = f2bf(s.z * inv); av.w = f2bf(s.w * inv);
    mv.x = f2bf(mx.x); mv.y = f2bf(mx.y); mv.z = f2bf(mx.z); mv.w = f2bf(mx.w);
    *(ushort4*)(rb + d)       = av;
    *(ushort4*)(rb + 300 + d) = mv;
}

// ---------------------------------------------------------------------------
// gemm1p (round-9 config, best measured): partials[nb] = relu(rep@W1+b1) @ W2
// 64x64 tile, BK=64, 1024 blocks -> 4/CU (TLP hides the barrier drains;
// round-10 showed 128x128 @ 1 block/CU regresses). LDS 32 KB dbuf,
// global_load_lds(16B). Fused epilogue -> partials[16][M][5], no atomics.
// ---------------------------------------------------------------------------
#define BM 64
#define BN 64
#define BK 64
#define GNB (NPAD / BN)   // 16

__global__ __launch_bounds__(256, 4) void gemm1p(
    const unsigned short* __restrict__ A,    // rep  [M][640] bf16
    const unsigned short* __restrict__ Bt,   // W1T  [1024][640] bf16
    const float* __restrict__ bias,          // b1 [1000]
    const unsigned short* __restrict__ W2t,  // [5][1024] bf16
    float* __restrict__ partials,            // [16][M][5]
    int M)
{
    __shared__ unsigned short As[2][BM * BK];   // 8 KB each buffer
    __shared__ unsigned short Bs[2][BN * BK];

    const int tid  = threadIdx.x;
    const int wv   = tid >> 6;
    const int lane = tid & 63;
    const int bm   = blockIdx.y * BM;
    const int bn   = blockIdx.x * BN;
    const int wr   = (wv & 1) * 32;
    const int wc   = (wv >> 1) * 32;

    f32x4 acc[2][2] = {};

    auto stage = [&](int buf, int k0) {
        #pragma unroll
        for (int j = 0; j < 2; ++j) {
            int ci  = (wv * 2 + j) * 64 + lane;
            int row = ci >> 3, c = ci & 7;
            const unsigned short* g = A + (size_t)(bm + row) * KPAD + k0 + c * 8;
            unsigned short* l = &As[buf][(wv * 2 + j) * 512];   // 1024 B / instr
            __builtin_amdgcn_global_load_lds(g, l, 16, 0, 0);
        }
        #pragma unroll
        for (int j = 0; j < 2; ++j) {
            int ci  = (wv * 2 + j) * 64 + lane;
            int row = ci >> 3, c = ci & 7;
            const unsigned short* g = Bt + (size_t)(bn + row) * KPAD + k0 + c * 8;
            unsigned short* l = &Bs[buf][(wv * 2 + j) * 512];
            __builtin_amdgcn_global_load_lds(g, l, 16, 0, 0);
        }
    };

    stage(0, 0);
    int cur = 0;
    const int q = lane >> 4, r16 = lane & 15;

    #pragma unroll 1
    for (int it = 0; it < KPAD / BK; ++it) {
        __syncthreads();
        if (it + 1 < KPAD / BK) stage(cur ^ 1, (it + 1) * BK);

        #pragma unroll
        for (int ks = 0; ks < BK; ks += 32) {
            bf16x8 af[2], bfr[2];
            #pragma unroll
            for (int mi = 0; mi < 2; ++mi)
                af[mi] = *(const bf16x8*)&As[cur][(wr + mi * 16 + r16) * BK + ks + q * 8];
            #pragma unroll
            for (int nj = 0; nj < 2; ++nj)
                bfr[nj] = *(const bf16x8*)&Bs[cur][(wc + nj * 16 + r16) * BK + ks + q * 8];
            #pragma unroll
            for (int mi = 0; mi < 2; ++mi)
                #pragma unroll
                for (int nj = 0; nj < 2; ++nj)
                    acc[mi][nj] = __builtin_amdgcn_mfma_f32_16x16x32_bf16(
                        af[mi], bfr[nj], acc[mi][nj], 0, 0, 0);
        }
        cur ^= 1;
    }

    // ---- fused epilogue: h -> partial logits ----
    float bv[2], w2v[2][NCLS];
    #pragma unroll
    for (int nj = 0; nj < 2; ++nj) {
        int n = bn + wc + nj * 16 + r16;
        if (n < HIDDEN) {
            bv[nj] = bias[n];
            #pragma unroll
            for (int c = 0; c < NCLS; ++c) w2v[nj][c] = bf2f(W2t[c * 1024 + n]);
        } else {
            bv[nj] = 0.f;
            #pragma unroll
            for (int c = 0; c < NCLS; ++c) w2v[nj][c] = 0.f;
        }
    }

    __syncthreads();                     // LDS reuse: As becomes float scratch
    float* pl = (float*)As;              // [4][32][5] floats

    #pragma unroll
    for (int mi = 0; mi < 2; ++mi) {
        #pragma unroll
        for (int r = 0; r < 4; ++r) {
            float p[NCLS] = {0.f, 0.f, 0.f, 0.f, 0.f};
            #pragma unroll
            for (int nj = 0; nj < 2; ++nj) {
                float h = fmaxf(acc[mi][nj][r] + bv[nj], 0.f);
                #pragma unroll
                for (int c = 0; c < NCLS; ++c) p[c] += h * w2v[nj][c];
            }
            #pragma unroll
            for (int off = 1; off < 16; off <<= 1)
                #pragma unroll
                for (int c = 0; c < NCLS; ++c)
                    p[c] += __shfl_xor(p[c], off, 64);
            if (r16 == 0) {
                int lr = mi * 16 + q * 4 + r;          // 0..31 within wave tile
                #pragma unroll
                for (int c = 0; c < NCLS; ++c)
                    pl[(wv * 32 + lr) * NCLS + c] = p[c];
            }
        }
    }
    __syncthreads();

    // combine wave pairs; 320 entries over 256 threads (strided).
    for (int e = tid; e < BM * NCLS; e += 256) {
        int lr = e / NCLS, c = e - lr * NCLS;
        float v;
        if (lr < 32) v = pl[(0 * 32 + lr) * NCLS + c] + pl[(2 * 32 + lr) * NCLS + c];
        else         v = pl[(1 * 32 + lr - 32) * NCLS + c] + pl[(3 * 32 + lr - 32) * NCLS + c];
        partials[(size_t)blockIdx.x * M * NCLS + (size_t)(bm + lr) * NCLS + c] = v;
    }
}

// ---------------------------------------------------------------------------
// reduce_out: out[m][c] = b2[c] + sum_nb partials[nb][m][c]
// ---------------------------------------------------------------------------
__global__ __launch_bounds__(256) void reduce_out(
    const float* __restrict__ partials, const float* __restrict__ b2,
    float* __restrict__ out, int M)
{
    const int i = blockIdx.x * 256 + threadIdx.x;
    if (i >= M * NCLS) return;
    const int c = i % NCLS;
    float s = b2[c];
    #pragma unroll
    for (int nb = 0; nb < GNB; ++nb)
        s += partials[(size_t)nb * M * NCLS + i];
    out[i] = s;
}

// ---------------------------------------------------------------------------
extern "C" void kernel_launch(void* const* d_in, const int* in_sizes, int n_in,
                              void* d_out, int out_size, void* d_ws, size_t ws_size,
                              hipStream_t stream)
{
    const int*   x       = (const int*)d_in[0];
    const int*   lengths = (const int*)d_in[1];
    const float* emb     = (const float*)d_in[2];
    const float* W1      = (const float*)d_in[3];
    const float* b1      = (const float*)d_in[4];
    const float* W2      = (const float*)d_in[5];
    const float* b2      = (const float*)d_in[6];
    float*       out     = (float*)d_out;

    const int B = in_sizes[1];               // 4096

    unsigned short* rep      = (unsigned short*)d_ws;         // [B][640]
    unsigned short* w1t      = rep + (size_t)B * KPAD;        // [1024][640]
    unsigned short* w2t      = w1t + (size_t)NPAD * KPAD;     // [5][1024]
    unsigned short* embb     = w2t + (size_t)NCLS * 1024;     // [50000][320]
    float*          partials = (float*)(embb + (size_t)VOCAB_SZ * EMBPAD); // [16][B][5]

    const size_t need = ((size_t)B * KPAD + (size_t)NPAD * KPAD + NCLS * 1024
                         + (size_t)VOCAB_SZ * EMBPAD) * 2
                        + (size_t)GNB * B * NCLS * 4;

    prep_all<<<CONV_BLOCKS + 660, 256, 0, stream>>>(emb, embb, W1, w1t, W2, w2t);

    if (ws_size >= need) {
        pool_bf16<<<B, 128, 0, stream>>>(x, lengths, embb, rep);
    } else {
        pool_f32<<<B, 128, 0, stream>>>(x, lengths, emb, rep);
    }

    dim3 g1(GNB, B / BM);                    // (16, 64) = 1024 blocks
    gemm1p<<<g1, 256, 0, stream>>>(rep, w1t, b1, w2t, partials, B);

    reduce_out<<<(B * NCLS + 255) / 256, 256, 0, stream>>>(partials, b2, out, B);
}

// Round 12
// 161.061 us; speedup vs baseline: 1.0256x; 1.0017x over previous
//
#include <hip/hip_runtime.h>
#include <float.h>
#include <stdint.h>

#define EMB_DIM  300
#define MAX_LEN  128
#define HIDDEN   1000
#define NCLS     5
#define VOCAB_SZ 50000
#define KPAD     640     // 600 padded to 10*64
#define NPAD     1024    // 1000 padded to 16*64
#define EMBPAD   320     // 300 dims padded to 320 shorts = 640 B = 5 x 128 B lines

typedef float    f32x4  __attribute__((ext_vector_type(4)));
typedef __bf16   bf16x8 __attribute__((ext_vector_type(8)));
typedef unsigned short ushort8v __attribute__((ext_vector_type(8)));

#define CONV_BLOCKS ((VOCAB_SZ * (EMBPAD / 4) + 255) / 256)   // 15625

__device__ __forceinline__ unsigned short f2bf(float f) {
    union { float f; uint32_t u; } v; v.f = f;
    uint32_t u = v.u;
    return (unsigned short)((u + 0x7FFFu + ((u >> 16) & 1u)) >> 16);   // RNE
}
__device__ __forceinline__ float bf2f(unsigned short h) {
    union { uint32_t u; float f; } v; v.u = ((uint32_t)h) << 16;
    return v.f;
}

// ---------------------------------------------------------------------------
// prep_all: one dispatch for emb conversion + both weight preps.
// ---------------------------------------------------------------------------
__global__ __launch_bounds__(256) void prep_all(
    const float* __restrict__ emb, unsigned short* __restrict__ embb,
    const float* __restrict__ W1, unsigned short* __restrict__ Bt,
    const float* __restrict__ W2, unsigned short* __restrict__ W2t)
{
    __shared__ float t[32][33];
    const int blk = blockIdx.x;

    if (blk < CONV_BLOCKS) {
        const int i = blk * 256 + threadIdx.x;     // chunk of 4 shorts
        if (i >= VOCAB_SZ * (EMBPAD / 4)) return;
        const int v  = i / (EMBPAD / 4);
        const int ch = i - v * (EMBPAD / 4);
        ushort4 o = {0, 0, 0, 0};
        if (ch < 75) {
            const float4 f = *(const float4*)(emb + (size_t)v * EMB_DIM + ch * 4);
            o.x = f2bf(f.x); o.y = f2bf(f.y); o.z = f2bf(f.z); o.w = f2bf(f.w);
        }
        *(ushort4*)(embb + (size_t)v * EMBPAD + ch * 4) = o;
        return;
    }
    const int pb = blk - CONV_BLOCKS;
    if (pb >= 640) {                               // W2T: 20 blocks
        const int i = (pb - 640) * 256 + threadIdx.x;    // [0, 5120)
        const int c = i >> 10, k = i & 1023;
        const float v = (k < HIDDEN) ? W2[(size_t)k * NCLS + c] : 0.f;
        W2t[(size_t)c * 1024 + k] = f2bf(v);
        return;
    }
    // W1 transpose: pb -> (px, py) in (32, 20)
    const int px = pb & 31, py = pb >> 5;
    const int tx = threadIdx.x & 31, ty = threadIdx.x >> 5;   // 32 x 8
    const int n0 = px * 32, k0 = py * 32;
    #pragma unroll
    for (int i = 0; i < 4; ++i) {
        int k = k0 + ty + i * 8, n = n0 + tx;
        t[ty + i * 8][tx] = (k < 600 && n < HIDDEN) ? W1[(size_t)k * HIDDEN + n] : 0.f;
    }
    __syncthreads();
    #pragma unroll
    for (int i = 0; i < 4; ++i) {
        int n = n0 + ty + i * 8, k = k0 + tx;
        Bt[(size_t)n * KPAD + k] = f2bf(t[tx][ty + i * 8]);
    }
}

// ---------------------------------------------------------------------------
// pool_bf16 (r9 config, best measured): gather + masked avg/max -> rep bf16.
// x2 unroll; x4 measured neutral (BW-floored at ~6.5 TB/s fabric rate).
// ---------------------------------------------------------------------------
__global__ __launch_bounds__(128) void pool_bf16(
    const int* __restrict__ x, const int* __restrict__ lengths,
    const unsigned short* __restrict__ embb, unsigned short* __restrict__ rep)
{
    const int b = blockIdx.x;
    const int t = threadIdx.x;

    __shared__ int sidx[MAX_LEN];
    sidx[t] = x[b * MAX_LEN + t];
    __syncthreads();

    unsigned short* rb = rep + (size_t)b * KPAD;

    if (t >= 75) {
        if (t < 85) {                      // zero pad cols 600..639
            ushort4 z = {0, 0, 0, 0};
            *(ushort4*)(rb + 600 + (t - 75) * 4) = z;
        }
        return;
    }

    int L = lengths[b];
    L = max(1, min(L, MAX_LEN));

    const int d = t * 4;
    float4 s  = {0.f, 0.f, 0.f, 0.f};
    float4 mx = {-FLT_MAX, -FLT_MAX, -FLT_MAX, -FLT_MAX};

    int i = 0;
    for (; i + 2 <= L; i += 2) {
        int i0 = max(0, min(sidx[i],     VOCAB_SZ - 1));
        int i1 = max(0, min(sidx[i + 1], VOCAB_SZ - 1));
        const ushort4 a = *(const ushort4*)(embb + (size_t)i0 * EMBPAD + d);
        const ushort4 c = *(const ushort4*)(embb + (size_t)i1 * EMBPAD + d);
        float a0 = bf2f(a.x), a1 = bf2f(a.y), a2 = bf2f(a.z), a3 = bf2f(a.w);
        float c0 = bf2f(c.x), c1 = bf2f(c.y), c2 = bf2f(c.z), c3 = bf2f(c.w);
        s.x += a0 + c0; s.y += a1 + c1; s.z += a2 + c2; s.w += a3 + c3;
        mx.x = fmaxf(mx.x, fmaxf(a0, c0)); mx.y = fmaxf(mx.y, fmaxf(a1, c1));
        mx.z = fmaxf(mx.z, fmaxf(a2, c2)); mx.w = fmaxf(mx.w, fmaxf(a3, c3));
    }
    if (i < L) {
        int i0 = max(0, min(sidx[i], VOCAB_SZ - 1));
        const ushort4 a = *(const ushort4*)(embb + (size_t)i0 * EMBPAD + d);
        float a0 = bf2f(a.x), a1 = bf2f(a.y), a2 = bf2f(a.z), a3 = bf2f(a.w);
        s.x += a0; s.y += a1; s.z += a2; s.w += a3;
        mx.x = fmaxf(mx.x, a0); mx.y = fmaxf(mx.y, a1);
        mx.z = fmaxf(mx.z, a2); mx.w = fmaxf(mx.w, a3);
    }

    const float inv = 1.0f / (float)L;
    ushort4 av, mv;
    av.x = f2bf(s.x * inv); av.y = f2bf(s.y * inv);
    av.z = f2bf(s.z * inv); av.w = f2bf(s.w * inv);
    mv.x = f2bf(mx.x); mv.y = f2bf(mx.y); mv.z = f2bf(mx.z); mv.w = f2bf(mx.w);
    *(ushort4*)(rb + d)       = av;     // avg -> [0,300)
    *(ushort4*)(rb + 300 + d) = mv;     // max -> [300,600)
}

// ---------------------------------------------------------------------------
// pool_f32 (fallback if ws too small for the bf16 table).
// ---------------------------------------------------------------------------
__global__ __launch_bounds__(128) void pool_f32(
    const int* __restrict__ x, const int* __restrict__ lengths,
    const float* __restrict__ emb, unsigned short* __restrict__ rep)
{
    const int b = blockIdx.x;
    const int t = threadIdx.x;

    __shared__ int sidx[MAX_LEN];
    sidx[t] = x[b * MAX_LEN + t];
    __syncthreads();

    unsigned short* rb = rep + (size_t)b * KPAD;

    if (t >= 75) {
        if (t < 85) {
            ushort4 z = {0, 0, 0, 0};
            *(ushort4*)(rb + 600 + (t - 75) * 4) = z;
        }
        return;
    }

    int L = lengths[b];
    L = max(1, min(L, MAX_LEN));

    const int d = t * 4;
    float4 s  = {0.f, 0.f, 0.f, 0.f};
    float4 mx = {-FLT_MAX, -FLT_MAX, -FLT_MAX, -FLT_MAX};

    for (int i = 0; i < L; ++i) {
        int idx = max(0, min(sidx[i], VOCAB_SZ - 1));
        const float4 v = *(const float4*)(emb + (size_t)idx * EMB_DIM + d);
        s.x += v.x; s.y += v.y; s.z += v.z; s.w += v.w;
        mx.x = fmaxf(mx.x, v.x); mx.y = fmaxf(mx.y, v.y);
        mx.z = fmaxf(mx.z, v.z); mx.w = fmaxf(mx.w, v.w);
    }

    const float inv = 1.0f / (float)L;
    ushort4 av, mv;
    av.x = f2bf(s.x * inv); av.y = f2bf(s.y * inv);
    av.z = f2bf(s.z * inv); av.w = f2bf(s.w * inv);
    mv.x = f2bf(mx.x); mv.y = f2bf(mx.y); mv.z = f2bf(mx.z); mv.w = f2bf(mx.w);
    *(ushort4*)(rb + d)       = av;
    *(ushort4*)(rb + 300 + d) = mv;
}

// ---------------------------------------------------------------------------
// gemm1p (r9 config + XCD swizzle): partials[nb] = relu(rep@W1+b1) @ W2.
// 64x64 tile, BK=64, 1024 blocks -> 4/CU. LDS 32 KB dbuf, global_load_lds.
// XCD swizzle: with round-robin id%8 -> XCD placement, map id so each XCD
// covers a contiguous 8-block m-range x all 16 n-blocks: per-XCD working
// set = 8x80 KB (A) + 1.31 MB (Bt) ~ 2 MB < 4 MB L2 (A was thrashing:
// default mapping streamed all 5.2 MB of A through every XCD's L2).
// ---------------------------------------------------------------------------
#define BM 64
#define BN 64
#define BK 64
#define GNB (NPAD / BN)   // 16

__global__ __launch_bounds__(256, 4) void gemm1p(
    const unsigned short* __restrict__ A,    // rep  [M][640] bf16
    const unsigned short* __restrict__ Bt,   // W1T  [1024][640] bf16
    const float* __restrict__ bias,          // b1 [1000]
    const unsigned short* __restrict__ W2t,  // [5][1024] bf16
    float* __restrict__ partials,            // [16][M][5]
    int M)
{
    __shared__ unsigned short As[2][BM * BK];   // 8 KB each buffer
    __shared__ unsigned short Bs[2][BN * BK];

    const int tid  = threadIdx.x;
    const int wv   = tid >> 6;
    const int lane = tid & 63;

    // ---- XCD-aware remap (bijective when gridDim.y % 8 == 0) ----
    const int nbt = gridDim.x;                     // 16
    const int mbt = gridDim.y;                     // 64
    const int id  = blockIdx.x + nbt * blockIdx.y; // dispatch-linear id
    int bmi, bni;
    if ((mbt & 7) == 0) {
        const int xcd = id & 7;
        const int s   = id >> 3;
        const int mpg = mbt >> 3;                  // m-blocks per XCD group (8)
        bmi = xcd * mpg + (s % mpg);
        bni = s / mpg;
    } else {
        bni = blockIdx.x; bmi = blockIdx.y;
    }
    const int bm = bmi * BM;
    const int bn = bni * BN;

    const int wr = (wv & 1) * 32;
    const int wc = (wv >> 1) * 32;

    f32x4 acc[2][2] = {};

    auto stage = [&](int buf, int k0) {
        #pragma unroll
        for (int j = 0; j < 2; ++j) {
            int ci  = (wv * 2 + j) * 64 + lane;
            int row = ci >> 3, c = ci & 7;
            const unsigned short* g = A + (size_t)(bm + row) * KPAD + k0 + c * 8;
            unsigned short* l = &As[buf][(wv * 2 + j) * 512];   // 1024 B / instr
            __builtin_amdgcn_global_load_lds(g, l, 16, 0, 0);
        }
        #pragma unroll
        for (int j = 0; j < 2; ++j) {
            int ci  = (wv * 2 + j) * 64 + lane;
            int row = ci >> 3, c = ci & 7;
            const unsigned short* g = Bt + (size_t)(bn + row) * KPAD + k0 + c * 8;
            unsigned short* l = &Bs[buf][(wv * 2 + j) * 512];
            __builtin_amdgcn_global_load_lds(g, l, 16, 0, 0);
        }
    };

    stage(0, 0);
    int cur = 0;
    const int q = lane >> 4, r16 = lane & 15;

    #pragma unroll 1
    for (int it = 0; it < KPAD / BK; ++it) {
        __syncthreads();
        if (it + 1 < KPAD / BK) stage(cur ^ 1, (it + 1) * BK);

        #pragma unroll
        for (int ks = 0; ks < BK; ks += 32) {
            bf16x8 af[2], bfr[2];
            #pragma unroll
            for (int mi = 0; mi < 2; ++mi)
                af[mi] = *(const bf16x8*)&As[cur][(wr + mi * 16 + r16) * BK + ks + q * 8];
            #pragma unroll
            for (int nj = 0; nj < 2; ++nj)
                bfr[nj] = *(const bf16x8*)&Bs[cur][(wc + nj * 16 + r16) * BK + ks + q * 8];
            #pragma unroll
            for (int mi = 0; mi < 2; ++mi)
                #pragma unroll
                for (int nj = 0; nj < 2; ++nj)
                    acc[mi][nj] = __builtin_amdgcn_mfma_f32_16x16x32_bf16(
                        af[mi], bfr[nj], acc[mi][nj], 0, 0, 0);
        }
        cur ^= 1;
    }

    // ---- fused epilogue: h -> partial logits ----
    float bv[2], w2v[2][NCLS];
    #pragma unroll
    for (int nj = 0; nj < 2; ++nj) {
        int n = bn + wc + nj * 16 + r16;
        if (n < HIDDEN) {
            bv[nj] = bias[n];
            #pragma unroll
            for (int c = 0; c < NCLS; ++c) w2v[nj][c] = bf2f(W2t[c * 1024 + n]);
        } else {
            bv[nj] = 0.f;
            #pragma unroll
            for (int c = 0; c < NCLS; ++c) w2v[nj][c] = 0.f;
        }
    }

    __syncthreads();                     // LDS reuse: As becomes float scratch
    float* pl = (float*)As;              // [4][32][5] floats

    #pragma unroll
    for (int mi = 0; mi < 2; ++mi) {
        #pragma unroll
        for (int r = 0; r < 4; ++r) {
            float p[NCLS] = {0.f, 0.f, 0.f, 0.f, 0.f};
            #pragma unroll
            for (int nj = 0; nj < 2; ++nj) {
                float h = fmaxf(acc[mi][nj][r] + bv[nj], 0.f);
                #pragma unroll
                for (int c = 0; c < NCLS; ++c) p[c] += h * w2v[nj][c];
            }
            #pragma unroll
            for (int off = 1; off < 16; off <<= 1)
                #pragma unroll
                for (int c = 0; c < NCLS; ++c)
                    p[c] += __shfl_xor(p[c], off, 64);
            if (r16 == 0) {
                int lr = mi * 16 + q * 4 + r;          // 0..31 within wave tile
                #pragma unroll
                for (int c = 0; c < NCLS; ++c)
                    pl[(wv * 32 + lr) * NCLS + c] = p[c];
            }
        }
    }
    __syncthreads();

    // combine wave pairs; 320 entries over 256 threads (strided).
    for (int e = tid; e < BM * NCLS; e += 256) {
        int lr = e / NCLS, c = e - lr * NCLS;
        float v;
        if (lr < 32) v = pl[(0 * 32 + lr) * NCLS + c] + pl[(2 * 32 + lr) * NCLS + c];
        else         v = pl[(1 * 32 + lr - 32) * NCLS + c] + pl[(3 * 32 + lr - 32) * NCLS + c];
        partials[(size_t)bni * M * NCLS + (size_t)(bm + lr) * NCLS + c] = v;
    }
}

// ---------------------------------------------------------------------------
// reduce_out: out[m][c] = b2[c] + sum_nb partials[nb][m][c]
// ---------------------------------------------------------------------------
__global__ __launch_bounds__(256) void reduce_out(
    const float* __restrict__ partials, const float* __restrict__ b2,
    float* __restrict__ out, int M)
{
    const int i = blockIdx.x * 256 + threadIdx.x;
    if (i >= M * NCLS) return;
    const int c = i % NCLS;
    float s = b2[c];
    #pragma unroll
    for (int nb = 0; nb < GNB; ++nb)
        s += partials[(size_t)nb * M * NCLS + i];
    out[i] = s;
}

// ---------------------------------------------------------------------------
extern "C" void kernel_launch(void* const* d_in, const int* in_sizes, int n_in,
                              void* d_out, int out_size, void* d_ws, size_t ws_size,
                              hipStream_t stream)
{
    const int*   x       = (const int*)d_in[0];
    const int*   lengths = (const int*)d_in[1];
    const float* emb     = (const float*)d_in[2];
    const float* W1      = (const float*)d_in[3];
    const float* b1      = (const float*)d_in[4];
    const float* W2      = (const float*)d_in[5];
    const float* b2      = (const float*)d_in[6];
    float*       out     = (float*)d_out;

    const int B = in_sizes[1];               // 4096

    unsigned short* rep      = (unsigned short*)d_ws;         // [B][640]
    unsigned short* w1t      = rep + (size_t)B * KPAD;        // [1024][640]
    unsigned short* w2t      = w1t + (size_t)NPAD * KPAD;     // [5][1024]
    unsigned short* embb     = w2t + (size_t)NCLS * 1024;     // [50000][320]
    float*          partials = (float*)(embb + (size_t)VOCAB_SZ * EMBPAD); // [16][B][5]

    const size_t need = ((size_t)B * KPAD + (size_t)NPAD * KPAD + NCLS * 1024
                         + (size_t)VOCAB_SZ * EMBPAD) * 2
                        + (size_t)GNB * B * NCLS * 4;

    prep_all<<<CONV_BLOCKS + 660, 256, 0, stream>>>(emb, embb, W1, w1t, W2, w2t);

    if (ws_size >= need) {
        pool_bf16<<<B, 128, 0, stream>>>(x, lengths, embb, rep);
    } else {
        pool_f32<<<B, 128, 0, stream>>>(x, lengths, emb, rep);
    }

    dim3 g1(GNB, B / BM);                    // (16, 64) = 1024 blocks
    gemm1p<<<g1, 256, 0, stream>>>(rep, w1t, b1, w2t, partials, B);

    reduce_out<<<(B * NCLS + 255) / 256, 256, 0, stream>>>(partials, b2, out, B);
}